// Round 1
// baseline (556.560 us; speedup 1.0000x reference)
//
#include <hip/hip_runtime.h>
#include <hip/hip_bf16.h>

#define NB    32      // batch
#define NCAP  2048    // input capsules (N)
#define CDIM  32      // output capsules (C)
#define LDIM  32      // capsule length (L)
#define ILEN  32      // input capsule length
#define CL    1024    // C*L

__device__ inline unsigned short f32_to_bf16_rne(float f) {
    unsigned int u = __float_as_uint(f);
    unsigned int r = 0x7FFFu + ((u >> 16) & 1u);
    u += r;
    return (unsigned short)(u >> 16);
}
__device__ inline float bf16_to_f32(unsigned short h) {
    return __uint_as_float(((unsigned int)h) << 16);
}

// ---------------------------------------------------------------------------
// Kernel A: u[b,j,k] = sum_i x[b,j,i] * W[j,i,k], stored bf16.
// Block = (j, k-quarter). LDS-stage W[j, :, 256-wide k slice] (32 KB) and
// x[:, j, :] (4 KB); each W element read from HBM exactly once.
// ---------------------------------------------------------------------------
__global__ __launch_bounds__(256) void compute_u(const float* __restrict__ x,
                                                 const float* __restrict__ W,
                                                 unsigned short* __restrict__ u) {
    const int j  = blockIdx.x >> 2;
    const int kq = blockIdx.x & 3;
    const int t  = threadIdx.x;

    __shared__ float wl[32 * 256];   // [i][k_local]
    __shared__ float xs[32 * 32];    // [b][i]

    // load W tile: rows i=0..31, cols kq*256..+255 (8192 floats)
    const float* Wj = W + (size_t)j * (ILEN * CL) + kq * 256;
#pragma unroll
    for (int it = 0; it < 8; ++it) {
        int f   = t + it * 256;        // float4 index
        int i   = f >> 6;
        int col = (f & 63) << 2;
        float4 v = *(const float4*)(Wj + (size_t)i * CL + col);
        *(float4*)(wl + i * 256 + col) = v;
    }
    // load x[b][i] for this j
    {
        int b = t >> 3;
        int i = (t & 7) << 2;
        float4 v = *(const float4*)(x + (size_t)b * (NCAP * ILEN) + (size_t)j * ILEN + i);
        *(float4*)(xs + b * 32 + i) = v;
    }
    __syncthreads();

    const int lane = t & 63;   // k position within slice (x4)
    const int wv   = t >> 6;   // b-group (8 b's per wave)

    float4 acc[8];
#pragma unroll
    for (int bb = 0; bb < 8; ++bb) acc[bb] = make_float4(0.f, 0.f, 0.f, 0.f);

#pragma unroll 4
    for (int i = 0; i < 32; ++i) {
        float4 w4 = *(const float4*)(wl + i * 256 + (lane << 2));
#pragma unroll
        for (int bb = 0; bb < 8; ++bb) {
            float xv = xs[(wv * 8 + bb) * 32 + i];   // wave-uniform -> LDS broadcast
            acc[bb].x += xv * w4.x;
            acc[bb].y += xv * w4.y;
            acc[bb].z += xv * w4.z;
            acc[bb].w += xv * w4.w;
        }
    }

    const int k = kq * 256 + (lane << 2);
#pragma unroll
    for (int bb = 0; bb < 8; ++bb) {
        int b = wv * 8 + bb;
        ushort4 o;
        o.x = f32_to_bf16_rne(acc[bb].x);
        o.y = f32_to_bf16_rne(acc[bb].y);
        o.z = f32_to_bf16_rne(acc[bb].z);
        o.w = f32_to_bf16_rne(acc[bb].w);
        *(ushort4*)(u + ((size_t)b * NCAP + j) * CL + k) = o;
    }
}

// ---------------------------------------------------------------------------
// Routing pass: for each (b,j): logits[c] = dot(u[b,j,c,:], vlog[b,c,:]),
// c = softmax_C(logits), accumulate s[b,c,l] += c[c]*u[b,j,c,l].
// With vlog = 0 this reproduces r=0's uniform 1/32 coupling exactly.
// Block = (b, chunk of 64 j). Thread t owns (c = t>>3, 4 l's).
// ---------------------------------------------------------------------------
__global__ __launch_bounds__(256) void route_pass(const unsigned short* __restrict__ u,
                                                  const float* __restrict__ vlog,
                                                  float* __restrict__ s_out) {
    const int b  = blockIdx.x;
    const int jc = blockIdx.y;
    const int t  = threadIdx.x;

    __shared__ float vl[1024];
    __shared__ float blog[32];
    __shared__ float cpl[32];

    {
        float4 v = *(const float4*)(vlog + b * 1024 + t * 4);
        *(float4*)(vl + t * 4) = v;
    }
    __syncthreads();

    const int c  = t >> 3;
    const int l4 = (t & 7) << 2;
    const float4 vme = *(const float4*)(vl + c * 32 + l4);

    float4 acc = make_float4(0.f, 0.f, 0.f, 0.f);
    const unsigned short* ub = u + ((size_t)b * NCAP + (size_t)jc * 64) * CL + t * 4;

    ushort4 uu = *(const ushort4*)(ub);   // prefetch jj=0
    for (int jj = 0; jj < 64; ++jj) {
        float4 uf;
        uf.x = bf16_to_f32(uu.x);
        uf.y = bf16_to_f32(uu.y);
        uf.z = bf16_to_f32(uu.z);
        uf.w = bf16_to_f32(uu.w);

        // prefetch next j's fragment before the barrier section
        ushort4 uu_next;
        if (jj + 1 < 64) uu_next = *(const ushort4*)(ub + (size_t)(jj + 1) * CL);

        // logit partial: dot over this thread's 4 l's, reduce over 8 lanes
        float p = uf.x * vme.x + uf.y * vme.y + uf.z * vme.z + uf.w * vme.w;
        p += __shfl_xor(p, 1, 64);
        p += __shfl_xor(p, 2, 64);
        p += __shfl_xor(p, 4, 64);
        if ((t & 7) == 0) blog[c] = p;
        __syncthreads();

        // wave 0 computes softmax over the 32 logits (lanes duplicated x2)
        if (t < 64) {
            int ci = t & 31;
            float val = blog[ci];
            float m = val;
            m = fmaxf(m, __shfl_xor(m, 16, 64));
            m = fmaxf(m, __shfl_xor(m, 8, 64));
            m = fmaxf(m, __shfl_xor(m, 4, 64));
            m = fmaxf(m, __shfl_xor(m, 2, 64));
            m = fmaxf(m, __shfl_xor(m, 1, 64));
            float e = __expf(val - m);
            float ssum = e;
            ssum += __shfl_xor(ssum, 16, 64);
            ssum += __shfl_xor(ssum, 8, 64);
            ssum += __shfl_xor(ssum, 4, 64);
            ssum += __shfl_xor(ssum, 2, 64);
            ssum += __shfl_xor(ssum, 1, 64);
            if (t < 32) cpl[ci] = e / ssum;
        }
        __syncthreads();

        float cw = cpl[c];
        acc.x += cw * uf.x;
        acc.y += cw * uf.y;
        acc.z += cw * uf.z;
        acc.w += cw * uf.w;
        uu = uu_next;
    }

    float* sp = s_out + b * 1024 + c * 32 + l4;
    atomicAdd(sp + 0, acc.x);
    atomicAdd(sp + 1, acc.y);
    atomicAdd(sp + 2, acc.z);
    atomicAdd(sp + 3, acc.w);
}

// ---------------------------------------------------------------------------
// Squash: v = (n^2/(1+n^2)/(n+eps)) * (s + biases), norm over L.
// Optionally emit vlog_out = v + vprev (running logit v-sum).
// Block = b; thread t owns (c = t>>3, 4 l's).
// ---------------------------------------------------------------------------
__global__ __launch_bounds__(256) void squash_kernel(const float* __restrict__ s,
                                                     const float* __restrict__ biases,
                                                     float* __restrict__ vout,
                                                     float* __restrict__ vlog_out,
                                                     const float* __restrict__ vprev) {
    const int b = blockIdx.x;
    const int t = threadIdx.x;

    float4 sv = *(const float4*)(s + b * 1024 + t * 4);
    float4 bi = *(const float4*)(biases + t * 4);
    sv.x += bi.x; sv.y += bi.y; sv.z += bi.z; sv.w += bi.w;

    float n2 = sv.x * sv.x + sv.y * sv.y + sv.z * sv.z + sv.w * sv.w;
    n2 += __shfl_xor(n2, 1, 64);
    n2 += __shfl_xor(n2, 2, 64);
    n2 += __shfl_xor(n2, 4, 64);

    float n = sqrtf(n2);
    float f = n2 / (1.f + n2) / (n + 1e-7f);

    float4 v;
    v.x = f * sv.x; v.y = f * sv.y; v.z = f * sv.z; v.w = f * sv.w;
    *(float4*)(vout + b * 1024 + t * 4) = v;

    if (vlog_out != nullptr) {
        float4 a = make_float4(0.f, 0.f, 0.f, 0.f);
        if (vprev != nullptr) a = *(const float4*)(vprev + b * 1024 + t * 4);
        float4 o;
        o.x = v.x + a.x; o.y = v.y + a.y; o.z = v.z + a.z; o.w = v.w + a.w;
        *(float4*)(vlog_out + b * 1024 + t * 4) = o;
    }
}

// ---------------------------------------------------------------------------
extern "C" void kernel_launch(void* const* d_in, const int* in_sizes, int n_in,
                              void* d_out, int out_size, void* d_ws, size_t ws_size,
                              hipStream_t stream) {
    const float* x      = (const float*)d_in[0];   // (32, 8, 8, 32, 32) = (B, N, iL)
    const float* W      = (const float*)d_in[1];   // (2048, 32, 1024)
    const float* biases = (const float*)d_in[2];   // (32, 32)
    float* out = (float*)d_out;                    // (32, 32, 32) fp32

    // workspace layout
    unsigned short* u = (unsigned short*)d_ws;                 // 64M bf16 = 128 MB
    float* fb = (float*)((char*)d_ws + (size_t)NB * NCAP * CL * 2);
    float* s0   = fb + 0 * 32768;
    float* s1   = fb + 1 * 32768;
    float* s2   = fb + 2 * 32768;
    float* zv   = fb + 3 * 32768;   // zero vlog for pass 0
    float* v0   = fb + 4 * 32768;
    float* vl2  = fb + 5 * 32768;   // v0 + v1 (cumulative logit v)
    float* vdmp = fb + 6 * 32768;   // v1 (unused downstream)

    // zero s0,s1,s2,zv (contiguous)
    hipMemsetAsync(fb, 0, 4 * 32768 * sizeof(float), stream);

    compute_u<<<NCAP * 4, 256, 0, stream>>>(x, W, u);

    dim3 rg(NB, 32);
    // r = 0: zero logits -> exact uniform 1/32 coupling
    route_pass<<<rg, 256, 0, stream>>>(u, zv, s0);
    squash_kernel<<<NB, 256, 0, stream>>>(s0, biases, v0, nullptr, nullptr);
    // r = 1: logits = u . v0
    route_pass<<<rg, 256, 0, stream>>>(u, v0, s1);
    squash_kernel<<<NB, 256, 0, stream>>>(s1, biases, vdmp, vl2, v0);
    // r = 2: logits = u . (v0 + v1)
    route_pass<<<rg, 256, 0, stream>>>(u, vl2, s2);
    squash_kernel<<<NB, 256, 0, stream>>>(s2, biases, out, nullptr, nullptr);
}

// Round 2
// 461.418 us; speedup vs baseline: 1.2062x; 1.2062x over previous
//
#include <hip/hip_runtime.h>
#include <hip/hip_bf16.h>

#define NB    32      // batch
#define NCAP  2048    // input capsules
#define CL    1024    // C*L
#define ILEN  32

__device__ inline unsigned short f32_to_bf16_rne(float f) {
    unsigned int u = __float_as_uint(f);
    u += 0x7FFFu + ((u >> 16) & 1u);
    return (unsigned short)(u >> 16);
}

__device__ inline void unpack8(uint4 a, float* f) {
    f[0] = __uint_as_float(a.x << 16);
    f[1] = __uint_as_float(a.x & 0xFFFF0000u);
    f[2] = __uint_as_float(a.y << 16);
    f[3] = __uint_as_float(a.y & 0xFFFF0000u);
    f[4] = __uint_as_float(a.z << 16);
    f[5] = __uint_as_float(a.z & 0xFFFF0000u);
    f[6] = __uint_as_float(a.w << 16);
    f[7] = __uint_as_float(a.w & 0xFFFF0000u);
}

// ---------------------------------------------------------------------------
// Kernel A: u[b,j,k] = sum_i x[b,j,i] * W[j,i,k], stored bf16.
// Block = (j, k-quarter). xs stored TRANSPOSED [i][b] so the per-i x-operand
// fetch is 2 broadcast ds_read_b128 (not 8 scalar b32) -> LDS pipe < VALU.
// ---------------------------------------------------------------------------
__global__ __launch_bounds__(256) void compute_u(const float* __restrict__ x,
                                                 const float* __restrict__ W,
                                                 unsigned short* __restrict__ u) {
    const int j  = blockIdx.x >> 2;
    const int kq = blockIdx.x & 3;
    const int t  = threadIdx.x;

    __shared__ float wl[32 * 256];   // [i][k_local]
    __shared__ float xs[32 * 32];    // [i][b]  (transposed!)

    const float* Wj = W + (size_t)j * (ILEN * CL) + kq * 256;
#pragma unroll
    for (int it = 0; it < 8; ++it) {
        int f   = t + it * 256;
        int i   = f >> 6;
        int col = (f & 63) << 2;
        *(float4*)(wl + i * 256 + col) = *(const float4*)(Wj + (size_t)i * CL + col);
    }
    {
        int b  = t >> 3;
        int i4 = (t & 7) << 2;
        float4 v = *(const float4*)(x + ((size_t)b * NCAP + j) * ILEN + i4);
        xs[(i4 + 0) * 32 + b] = v.x;
        xs[(i4 + 1) * 32 + b] = v.y;
        xs[(i4 + 2) * 32 + b] = v.z;
        xs[(i4 + 3) * 32 + b] = v.w;
    }
    __syncthreads();

    const int lane = t & 63;   // k chunk within slice
    const int wv   = t >> 6;   // b-octet

    float acc[8][4];
#pragma unroll
    for (int bb = 0; bb < 8; ++bb)
#pragma unroll
        for (int q = 0; q < 4; ++q) acc[bb][q] = 0.f;

#pragma unroll 4
    for (int i = 0; i < 32; ++i) {
        float4 w4 = *(const float4*)(wl + i * 256 + (lane << 2));
        float4 xa = *(const float4*)(xs + i * 32 + wv * 8);       // broadcast
        float4 xb = *(const float4*)(xs + i * 32 + wv * 8 + 4);   // broadcast
        float xv[8] = {xa.x, xa.y, xa.z, xa.w, xb.x, xb.y, xb.z, xb.w};
#pragma unroll
        for (int bb = 0; bb < 8; ++bb) {
            acc[bb][0] += xv[bb] * w4.x;
            acc[bb][1] += xv[bb] * w4.y;
            acc[bb][2] += xv[bb] * w4.z;
            acc[bb][3] += xv[bb] * w4.w;
        }
    }

    const int k = kq * 256 + (lane << 2);
#pragma unroll
    for (int bb = 0; bb < 8; ++bb) {
        int b = wv * 8 + bb;
        ushort4 o;
        o.x = f32_to_bf16_rne(acc[bb][0]);
        o.y = f32_to_bf16_rne(acc[bb][1]);
        o.z = f32_to_bf16_rne(acc[bb][2]);
        o.w = f32_to_bf16_rne(acc[bb][3]);
        *(ushort4*)(u + ((size_t)b * NCAP + j) * CL + k) = o;
    }
}

// ---------------------------------------------------------------------------
// Routing pass, barrier-free inner loop. Lane i owns c0 = i>>2 (l = (i&3)*8..+8)
// and c1 = c0+16. Softmax over C done entirely with shfl_xor; every wave does
// its own softmax (no idle waves). Depth-2 prefetch. Block writes an
// atomic-free partial s to spart[b][jc][1024].
// ---------------------------------------------------------------------------
template<bool HAS_V>
__global__ __launch_bounds__(256) void route_pass(const unsigned short* __restrict__ u,
                                                  const float* __restrict__ vlog,
                                                  float* __restrict__ spart) {
    const int b    = blockIdx.x;
    const int jc   = blockIdx.y;
    const int t    = threadIdx.x;
    const int wv   = t >> 6;
    const int lane = t & 63;
    const int c0   = lane >> 2;           // 0..15
    const int sub  = lane & 3;
    const int e0   = c0 * 32 + sub * 8;   // element offset of fragment 0
    // fragment 1 lives at e0 + 512 (capsule c0+16)

    float vme0[8], vme1[8];
    if (HAS_V) {
        const float* vb = vlog + b * CL;
        *(float4*)(vme0)     = *(const float4*)(vb + e0);
        *(float4*)(vme0 + 4) = *(const float4*)(vb + e0 + 4);
        *(float4*)(vme1)     = *(const float4*)(vb + e0 + 512);
        *(float4*)(vme1 + 4) = *(const float4*)(vb + e0 + 516);
    }

    const int jbase = jc * 128 + wv * 32;
    const unsigned short* ub = u + ((size_t)b * NCAP + jbase) * CL;

    float acc0[8], acc1[8];
#pragma unroll
    for (int e = 0; e < 8; ++e) { acc0[e] = 0.f; acc1[e] = 0.f; }

    // depth-2 software pipeline
    uint4 a0 = *(const uint4*)(ub + 0 * CL + e0);
    uint4 g0 = *(const uint4*)(ub + 0 * CL + e0 + 512);
    uint4 a1 = *(const uint4*)(ub + 1 * CL + e0);
    uint4 g1 = *(const uint4*)(ub + 1 * CL + e0 + 512);

    for (int jj = 0; jj < 32; ++jj) {
        int jn = (jj + 2 < 32) ? (jj + 2) : 31;
        uint4 a2 = *(const uint4*)(ub + (size_t)jn * CL + e0);
        uint4 g2 = *(const uint4*)(ub + (size_t)jn * CL + e0 + 512);

        float uf0[8], uf1[8];
        unpack8(a0, uf0);
        unpack8(g0, uf1);

        float cw0, cw1;
        if (HAS_V) {
            float p0 = 0.f, p1 = 0.f;
#pragma unroll
            for (int e = 0; e < 8; ++e) { p0 += uf0[e] * vme0[e]; p1 += uf1[e] * vme1[e]; }
            p0 += __shfl_xor(p0, 1); p0 += __shfl_xor(p0, 2);
            p1 += __shfl_xor(p1, 1); p1 += __shfl_xor(p1, 2);
            float m = fmaxf(p0, p1);
            m = fmaxf(m, __shfl_xor(m, 4));
            m = fmaxf(m, __shfl_xor(m, 8));
            m = fmaxf(m, __shfl_xor(m, 16));
            m = fmaxf(m, __shfl_xor(m, 32));
            float ex0 = __expf(p0 - m);
            float ex1 = __expf(p1 - m);
            float ssum = ex0 + ex1;
            ssum += __shfl_xor(ssum, 4);
            ssum += __shfl_xor(ssum, 8);
            ssum += __shfl_xor(ssum, 16);
            ssum += __shfl_xor(ssum, 32);
            float inv = __builtin_amdgcn_rcpf(ssum);
            cw0 = ex0 * inv;
            cw1 = ex1 * inv;
        } else {
            cw0 = 0.03125f;
            cw1 = 0.03125f;
        }
#pragma unroll
        for (int e = 0; e < 8; ++e) {
            acc0[e] += cw0 * uf0[e];
            acc1[e] += cw1 * uf1[e];
        }
        a0 = a1; g0 = g1; a1 = a2; g1 = g2;
    }

    // block reduction (no atomics): 4 waves -> one partial vector
    __shared__ float red[4][1024];
    *(float4*)(&red[wv][e0])       = *(float4*)(acc0);
    *(float4*)(&red[wv][e0 + 4])   = *(float4*)(acc0 + 4);
    *(float4*)(&red[wv][e0 + 512]) = *(float4*)(acc1);
    *(float4*)(&red[wv][e0 + 516]) = *(float4*)(acc1 + 4);
    __syncthreads();

    const int o = t * 4;
    float4 r0 = *(float4*)(&red[0][o]);
    float4 r1 = *(float4*)(&red[1][o]);
    float4 r2 = *(float4*)(&red[2][o]);
    float4 r3 = *(float4*)(&red[3][o]);
    float4 r;
    r.x = (r0.x + r1.x) + (r2.x + r3.x);
    r.y = (r0.y + r1.y) + (r2.y + r3.y);
    r.z = (r0.z + r1.z) + (r2.z + r3.z);
    r.w = (r0.w + r1.w) + (r2.w + r3.w);
    *(float4*)(spart + ((size_t)b * 16 + jc) * CL + o) = r;
}

// ---------------------------------------------------------------------------
// Squash: sums the 16 per-jc partials, adds biases, squashes.
// Optionally emits vlog_out = v + vprev (cumulative logit v).
// ---------------------------------------------------------------------------
__global__ __launch_bounds__(256) void squash_kernel(const float* __restrict__ spart,
                                                     const float* __restrict__ biases,
                                                     float* __restrict__ vout,
                                                     float* __restrict__ vlog_out,
                                                     const float* __restrict__ vprev) {
    const int b = blockIdx.x;
    const int t = threadIdx.x;

    float4 sv = make_float4(0.f, 0.f, 0.f, 0.f);
#pragma unroll
    for (int p = 0; p < 16; ++p) {
        float4 q = *(const float4*)(spart + ((size_t)b * 16 + p) * CL + t * 4);
        sv.x += q.x; sv.y += q.y; sv.z += q.z; sv.w += q.w;
    }
    float4 bi = *(const float4*)(biases + t * 4);
    sv.x += bi.x; sv.y += bi.y; sv.z += bi.z; sv.w += bi.w;

    float n2 = sv.x * sv.x + sv.y * sv.y + sv.z * sv.z + sv.w * sv.w;
    n2 += __shfl_xor(n2, 1);
    n2 += __shfl_xor(n2, 2);
    n2 += __shfl_xor(n2, 4);

    float n = sqrtf(n2);
    float f = n2 / ((1.f + n2) * (n + 1e-7f));

    float4 v;
    v.x = f * sv.x; v.y = f * sv.y; v.z = f * sv.z; v.w = f * sv.w;
    *(float4*)(vout + b * CL + t * 4) = v;

    if (vlog_out != nullptr) {
        float4 a = make_float4(0.f, 0.f, 0.f, 0.f);
        if (vprev != nullptr) a = *(const float4*)(vprev + b * CL + t * 4);
        float4 o;
        o.x = v.x + a.x; o.y = v.y + a.y; o.z = v.z + a.z; o.w = v.w + a.w;
        *(float4*)(vlog_out + b * CL + t * 4) = o;
    }
}

// ---------------------------------------------------------------------------
extern "C" void kernel_launch(void* const* d_in, const int* in_sizes, int n_in,
                              void* d_out, int out_size, void* d_ws, size_t ws_size,
                              hipStream_t stream) {
    const float* x      = (const float*)d_in[0];   // (32, 2048, 32)
    const float* W      = (const float*)d_in[1];   // (2048, 32, 1024)
    const float* biases = (const float*)d_in[2];   // (32, 32)
    float* out = (float*)d_out;                    // (32, 32, 32)

    unsigned short* u = (unsigned short*)d_ws;                     // 128 MB bf16
    float* fb    = (float*)((char*)d_ws + (size_t)NB * NCAP * CL * 2);
    float* spart = fb;                  // 32*16*1024 = 524288 floats
    float* v0    = spart + 524288;
    float* vl2   = v0 + 32768;
    float* vdmp  = vl2 + 32768;

    compute_u<<<NCAP * 4, 256, 0, stream>>>(x, W, u);

    dim3 rg(NB, 16);
    // r = 0: zero logits -> coupling exactly 1/32, no softmax needed
    route_pass<false><<<rg, 256, 0, stream>>>(u, nullptr, spart);
    squash_kernel<<<NB, 256, 0, stream>>>(spart, biases, v0, nullptr, nullptr);
    // r = 1: logits = u . v0
    route_pass<true><<<rg, 256, 0, stream>>>(u, v0, spart);
    squash_kernel<<<NB, 256, 0, stream>>>(spart, biases, vdmp, vl2, v0);
    // r = 2: logits = u . (v0 + v1)
    route_pass<true><<<rg, 256, 0, stream>>>(u, vl2, spart);
    squash_kernel<<<NB, 256, 0, stream>>>(spart, biases, out, nullptr, nullptr);
}